// Round 4
// baseline (86.382 us; speedup 1.0000x reference)
//
#include <hip/hip_runtime.h>
#include <stdint.h>

typedef unsigned long long u64;

// Binarized MLP: every matmul is sign(x) @ sign(w)^T => XOR+popcount on
// bit-packed rows: dot = K - 2*popcount(xa ^ xw).
// Round 4: 8x8 register tiling. Wave owns 8 rows x 512 cols; lane owns
// 8 cols (lane + 64*cb) x 8 rows -> cnt[8][8]. Weights streamed per-k from
// global (L2-resident), acts broadcast from wave-private LDS. Loads/MAC =
// 0.25 (vs 1.5 in round 3, which remat'd weight loads per row: VGPR=60
// couldn't hold 52 weight regs). Rows wave-private => ZERO __syncthreads.

#define NB   16384
#define DIN  784
#define HID  512
#define DOUT 10
#define KW1  13      // ceil(784/64)
#define KW2  8       // 512/64
#define PST  14      // padded L1 act row stride (u64), keeps b128 16B-aligned
#define WPW  240     // per-wave LDS u64: A1 8*14=112 | A2 64 | A3 64

// ---------------- combined weight pack (one dispatch; proven r3) ----------
// w1/w2/w3 transposed-packed WT[k*HID + col] (word k bit l = w[col][64k+l]);
// w4 row-packed. Pad bits (784 tail) = 0 on both operands.
__global__ void bmlp_pack_w(const float* __restrict__ w1, const float* __restrict__ w2,
                            const float* __restrict__ w3, const float* __restrict__ w4,
                            u64* __restrict__ W1T, u64* __restrict__ W2T,
                            u64* __restrict__ W3T, u64* __restrict__ W4p)
{
    int gw   = (int)((blockIdx.x * blockDim.x + threadIdx.x) >> 6);
    int lane = threadIdx.x & 63;

    if (gw < HID * KW1) {                       // w1: [512][784] -> W1T[13][512]
        int r = gw / KW1, k = gw - r * KW1;
        int e = k * 64 + lane;
        float v = (e < DIN) ? w1[r * DIN + e] : 1.0f;   // pad -> bit 0
        u64 word = __ballot(v < 0.0f);
        if (lane == 0) W1T[k * HID + r] = word;
        return;
    }
    gw -= HID * KW1;
    if (gw < HID * KW2) {                       // w2 -> W2T[8][512]
        int r = gw >> 3, k = gw & 7;
        float v = w2[r * HID + k * 64 + lane];
        u64 word = __ballot(v < 0.0f);
        if (lane == 0) W2T[k * HID + r] = word;
        return;
    }
    gw -= HID * KW2;
    if (gw < HID * KW2) {                       // w3
        int r = gw >> 3, k = gw & 7;
        float v = w3[r * HID + k * 64 + lane];
        u64 word = __ballot(v < 0.0f);
        if (lane == 0) W3T[k * HID + r] = word;
        return;
    }
    gw -= HID * KW2;
    if (gw < DOUT * KW2) {                      // w4: [10][512] -> W4p[10][8]
        int r = gw >> 3, k = gw & 7;
        float v = w4[r * HID + k * 64 + lane];
        u64 word = __ballot(v < 0.0f);
        if (lane == 0) W4p[r * KW2 + k] = word;
    }
}

// One binarized layer with 8x8 register tile.
// act:   LDS, rows [8][ASTR] (wave-private), read as wave-broadcast.
// actOut:LDS, [8][8] packed next-layer acts (index r*8+k).
// WT:    global [KW][HID], L2-resident; per-k loads coalesced across lanes.
// BN epilogue in exact reference op order (proven r1/r3):
//   A = g * (1/sqrt(v+eps));  y = ((dot + b) - m) * A + be;  sign -> ballot.
template<int KW, int ASTR>
__device__ __forceinline__ void bin_layer(
    const u64* act, u64* actOut, const u64* __restrict__ WT,
    const float* __restrict__ b, const float* __restrict__ g,
    const float* __restrict__ be, const float* __restrict__ m,
    const float* __restrict__ v, float eps, int K, int lane)
{
    int cnt[8][8];                              // [cb][r], statically indexed
#pragma unroll
    for (int cb = 0; cb < 8; ++cb)
#pragma unroll
        for (int r = 0; r < 8; ++r) cnt[cb][r] = 0;

#pragma unroll
    for (int kp = 0; kp < KW / 2; ++kp) {       // k-pairs: b128 act reads
        const int k0 = 2 * kp;
        u64 wv0[8], wv1[8];
#pragma unroll
        for (int cb = 0; cb < 8; ++cb) {        // coalesced 512B loads
            wv0[cb] = WT[k0 * HID + cb * 64 + lane];
            wv1[cb] = WT[(k0 + 1) * HID + cb * 64 + lane];
        }
#pragma unroll
        for (int r = 0; r < 8; ++r) {
            ulonglong2 a = *reinterpret_cast<const ulonglong2*>(&act[r * ASTR + k0]);
#pragma unroll
            for (int cb = 0; cb < 8; ++cb) {
                cnt[cb][r] += (int)__popcll(a.x ^ wv0[cb]);
                cnt[cb][r] += (int)__popcll(a.y ^ wv1[cb]);
            }
        }
    }
    if (KW & 1) {                               // tail word (layer 1, k=12)
        const int kt = KW - 1;
        u64 wv[8];
#pragma unroll
        for (int cb = 0; cb < 8; ++cb) wv[cb] = WT[kt * HID + cb * 64 + lane];
#pragma unroll
        for (int r = 0; r < 8; ++r) {
            u64 a = act[r * ASTR + kt];
#pragma unroll
            for (int cb = 0; cb < 8; ++cb)
                cnt[cb][r] += (int)__popcll(a ^ wv[cb]);
        }
    }

    // BN params for my 8 cols (coalesced, loaded after MACs to limit liveness)
    float pb[8], pm[8], pe[8], pA[8];
#pragma unroll
    for (int cb = 0; cb < 8; ++cb) {
        int c = cb * 64 + lane;
        pb[cb] = b[c]; pm[cb] = m[c]; pe[cb] = be[c];
        pA[cb] = __fmul_rn(g[c], __fdiv_rn(1.0f, __fsqrt_rn(__fadd_rn(v[c], eps))));
    }

    // epilogue: 64 ballots; lane L = r*8+cb keeps word (r,cb); one write/lane
    u64 myword = 0;
#pragma unroll
    for (int r = 0; r < 8; ++r) {
#pragma unroll
        for (int cb = 0; cb < 8; ++cb) {
            float dotf = (float)(K - 2 * cnt[cb][r]);   // exact integer
            float xl = __fadd_rn(dotf, pb[cb]);
            float y  = __fadd_rn(__fmul_rn(__fsub_rn(xl, pm[cb]), pA[cb]), pe[cb]);
            u64 bal = __ballot(y < 0.0f);               // bit=1 <=> -1
            myword = (lane == r * 8 + cb) ? bal : myword;
        }
    }
    actOut[lane] = myword;                      // coalesced; next reads r*8+k
}

__global__ __launch_bounds__(256, 2)
void bmlp_fused(const float* __restrict__ x,
                const u64* __restrict__ W1T, const u64* __restrict__ W2T,
                const u64* __restrict__ W3T, const u64* __restrict__ W4p,
                const float* __restrict__ b1, const float* __restrict__ g1,
                const float* __restrict__ be1, const float* __restrict__ m1,
                const float* __restrict__ v1,
                const float* __restrict__ b2, const float* __restrict__ g2,
                const float* __restrict__ be2, const float* __restrict__ m2,
                const float* __restrict__ v2,
                const float* __restrict__ b3, const float* __restrict__ g3,
                const float* __restrict__ be3, const float* __restrict__ m3,
                const float* __restrict__ v3,
                const float* __restrict__ b4,
                float* __restrict__ out)
{
    __shared__ __align__(16) u64 lds[4][WPW];
    const int t = threadIdx.x, w = t >> 6, lane = t & 63;
    const int row0 = blockIdx.x * 32 + w * 8;   // wave-private 8 rows

    u64* A1 = lds[w];                           // [8][PST]
    u64* A2 = lds[w] + 8 * PST;                 // [8][8]
    u64* A3 = lds[w] + 8 * PST + 64;            // [8][8]

    // pack my 8 x-rows (ballot straight to private LDS; no barrier needed)
#pragma unroll 2
    for (int r = 0; r < 8; ++r) {
        const float* xr = x + (size_t)(row0 + r) * DIN;
#pragma unroll
        for (int k = 0; k < KW1; ++k) {
            int e = k * 64 + lane;
            float vx = (e < DIN) ? xr[e] : 1.0f;        // pad -> bit 0
            u64 word = __ballot(vx < 0.0f);
            if (lane == 0) A1[r * PST + k] = word;
        }
    }

    bin_layer<KW1, PST>(A1, A2, W1T, b1, g1, be1, m1, v1, 1e-5f, DIN, lane);
    bin_layer<KW2, 8 >(A2, A3, W2T, b2, g2, be2, m2, v2, 1e-5f, HID, lane);
    bin_layer<KW2, 8 >(A3, A2, W3T, b3, g3, be3, m3, v3, 512.0f, HID, lane); // EPS3 bug: 512

    // layer 4: out = dot + b4. pass1: r=lane>>3 (broadcast LDS), c=lane&7.
    {
        int r = lane >> 3, c = lane & 7;
        int mm = 0;
#pragma unroll
        for (int k = 0; k < KW2; ++k)
            mm += (int)__popcll(A2[r * 8 + k] ^ W4p[c * KW2 + k]);
        out[(size_t)(row0 + r) * DOUT + c] = __fadd_rn((float)(HID - 2 * mm), b4[c]);
    }
    if (lane < 16) {                            // pass 2: cols 8,9
        int r = lane >> 1, c = 8 + (lane & 1);
        int mm = 0;
#pragma unroll
        for (int k = 0; k < KW2; ++k)
            mm += (int)__popcll(A2[r * 8 + k] ^ W4p[c * KW2 + k]);
        out[(size_t)(row0 + r) * DOUT + c] = __fadd_rn((float)(HID - 2 * mm), b4[c]);
    }
}

extern "C" void kernel_launch(void* const* d_in, const int* in_sizes, int n_in,
                              void* d_out, int out_size, void* d_ws, size_t ws_size,
                              hipStream_t stream)
{
    const float* x   = (const float*)d_in[0];
    const float* w1  = (const float*)d_in[1];
    const float* b1  = (const float*)d_in[2];
    const float* g1  = (const float*)d_in[3];
    const float* be1 = (const float*)d_in[4];
    const float* m1  = (const float*)d_in[5];
    const float* v1  = (const float*)d_in[6];
    const float* w2  = (const float*)d_in[7];
    const float* b2  = (const float*)d_in[8];
    const float* g2  = (const float*)d_in[9];
    const float* be2 = (const float*)d_in[10];
    const float* m2  = (const float*)d_in[11];
    const float* v2  = (const float*)d_in[12];
    const float* w3  = (const float*)d_in[13];
    const float* b3  = (const float*)d_in[14];
    const float* g3  = (const float*)d_in[15];
    const float* be3 = (const float*)d_in[16];
    const float* m3  = (const float*)d_in[17];
    const float* v3  = (const float*)d_in[18];
    const float* w4  = (const float*)d_in[19];
    const float* b4  = (const float*)d_in[20];
    float* out = (float*)d_out;

    // workspace: packed weights only (~119 KB)
    u64* W1T = (u64*)d_ws;
    u64* W2T = W1T + (size_t)KW1 * HID;
    u64* W3T = W2T + (size_t)KW2 * HID;
    u64* W4p = W3T + (size_t)KW2 * HID;

    const int packWaves = HID * KW1 + 2 * HID * KW2 + DOUT * KW2;
    bmlp_pack_w<<<dim3((packWaves * 64 + 255) / 256), 256, 0, stream>>>(
        w1, w2, w3, w4, W1T, W2T, W3T, W4p);

    bmlp_fused<<<dim3(NB / 32), 256, 0, stream>>>(
        x, W1T, W2T, W3T, W4p,
        b1, g1, be1, m1, v1,
        b2, g2, be2, m2, v2,
        b3, g3, be3, m3, v3,
        b4, out);
}